// Round 1
// baseline (518.958 us; speedup 1.0000x reference)
//
#include <hip/hip_runtime.h>

typedef unsigned int uint32;

#define B_DIM 4
#define C_IN  32
#define C_OUT 64
#define E_DIM 200000
#define KNB   5

// ---- bf16 helpers (RNE pack, cheap unpack) --------------------------------
__device__ __forceinline__ unsigned short f2bf_rne(float f) {
  uint32 u = __float_as_uint(f);
  u += 0x7fffu + ((u >> 16) & 1u);
  return (unsigned short)(u >> 16);
}
__device__ __forceinline__ float bf_lo(uint32 u) { return __uint_as_float(u << 16); }
__device__ __forceinline__ float bf_hi(uint32 u) { return __uint_as_float(u & 0xffff0000u); }

// ---- kernel 1: transpose x (B,C,E) f32 -> xT (B,E,C) packed bf16 ----------
// one block per (64-edge tile, b); E_DIM = 64*3125 exactly.
__global__ __launch_bounds__(256) void xpose_kernel(const float* __restrict__ x,
                                                    uint32* __restrict__ xT) {
  __shared__ float tile[C_IN][64 + 1];  // +1 pad: kill bank conflicts
  const int b = blockIdx.y;
  const long e0 = (long)blockIdx.x * 64;
  const int t = threadIdx.x;
  const int e_r = t & 63, c_r = t >> 6;  // coalesced read: consecutive t -> consecutive e
#pragma unroll
  for (int r = 0; r < 8; ++r) {
    const int c = c_r + r * 4;
    tile[c][e_r] = x[((long)b * C_IN + c) * E_DIM + e0 + e_r];
  }
  __syncthreads();
  const int u = t & 15;      // packed-pair index (channels 2u, 2u+1)
  const int e_w = t >> 4;    // coalesced write: consecutive t -> consecutive u
#pragma unroll
  for (int r = 0; r < 4; ++r) {
    const int e_l = e_w + r * 16;
    const float f0 = tile[2 * u][e_l];
    const float f1 = tile[2 * u + 1][e_l];
    const uint32 p = (uint32)f2bf_rne(f0) | ((uint32)f2bf_rne(f1) << 16);
    xT[((long)b * E_DIM + e0 + e_l) * 16 + u] = p;  // one row = 64 B = 1 cacheline
  }
}

// ---- kernel 2: W (O,C,1,K) -> Wt[k][c][o] so o is the fast axis -----------
__global__ __launch_bounds__(256) void prep_w(const float* __restrict__ W,
                                              float* __restrict__ Wt) {
  const int i = blockIdx.x * 256 + threadIdx.x;
  if (i < C_OUT * C_IN * KNB) {
    const int o = i % C_OUT;
    const int c = (i / C_OUT) % C_IN;
    const int k = i / (C_OUT * C_IN);
    Wt[i] = W[o * (C_IN * KNB) + c * KNB + k];
  }
}

// ---- kernel 3: main. one thread per (b, e); 64 fp32 accumulators ----------
// W reads are thread-uniform -> scalar loads on the SMEM pipe; the VALU does
// almost nothing but v_fmac.
__global__ __launch_bounds__(256) void mesh_main(const uint32* __restrict__ xT,
                                                 const int* __restrict__ Gi,
                                                 const float* __restrict__ Wt,
                                                 const float* __restrict__ bias,
                                                 float* __restrict__ out) {
  const int b = blockIdx.y;
  const int e = blockIdx.x * 256 + threadIdx.x;
  if (e >= E_DIM) return;
  const long be = (long)b * E_DIM;
  const int* gp = Gi + (be + e) * KNB;
  const int n0 = gp[0], n1 = gp[1], n2 = gp[2], n3 = gp[3], n4 = gp[4];
  const uint4* r0 = (const uint4*)(xT + (be + n0) * 16);
  const uint4* r1 = (const uint4*)(xT + (be + n1) * 16);
  const uint4* r2 = (const uint4*)(xT + (be + n2) * 16);
  const uint4* r3 = (const uint4*)(xT + (be + n3) * 16);
  const uint4* r4 = (const uint4*)(xT + (be + n4) * 16);

  float acc[C_OUT];
#pragma unroll
  for (int o = 0; o < C_OUT; ++o) acc[o] = 0.f;

  // ---- component 0: G = f0 ----
#pragma unroll 1
  for (int w = 0; w < 4; ++w) {
    const uint4 a = r0[w];
    const uint32 ua[4] = {a.x, a.y, a.z, a.w};
#pragma unroll
    for (int tq = 0; tq < 4; ++tq) {
      const int ch = w * 8 + tq * 2;
      const float g0 = bf_lo(ua[tq]);
      const float g1 = bf_hi(ua[tq]);
      const float* wp = Wt + (0 * C_IN + ch) * C_OUT;
#pragma unroll
      for (int o = 0; o < C_OUT; ++o) acc[o] += g0 * wp[o];
#pragma unroll
      for (int o = 0; o < C_OUT; ++o) acc[o] += g1 * wp[C_OUT + o];
    }
  }

  // ---- components 1 & 3: f1+f3, |f1-f3| ----
#pragma unroll 1
  for (int w = 0; w < 4; ++w) {
    const uint4 a = r1[w];
    const uint4 c4 = r3[w];
    const uint32 ua[4] = {a.x, a.y, a.z, a.w};
    const uint32 ub[4] = {c4.x, c4.y, c4.z, c4.w};
#pragma unroll
    for (int tq = 0; tq < 4; ++tq) {
      const int ch = w * 8 + tq * 2;
      const float a0 = bf_lo(ua[tq]), a1 = bf_hi(ua[tq]);
      const float b0 = bf_lo(ub[tq]), b1 = bf_hi(ub[tq]);
      const float s0 = a0 + b0, s1 = a1 + b1;
      const float d0 = fabsf(a0 - b0), d1 = fabsf(a1 - b1);
      const float* wps = Wt + (1 * C_IN + ch) * C_OUT;
      const float* wpd = Wt + (3 * C_IN + ch) * C_OUT;
#pragma unroll
      for (int o = 0; o < C_OUT; ++o) acc[o] += s0 * wps[o];
#pragma unroll
      for (int o = 0; o < C_OUT; ++o) acc[o] += s1 * wps[C_OUT + o];
#pragma unroll
      for (int o = 0; o < C_OUT; ++o) acc[o] += d0 * wpd[o];
#pragma unroll
      for (int o = 0; o < C_OUT; ++o) acc[o] += d1 * wpd[C_OUT + o];
    }
  }

  // ---- components 2 & 4: f2+f4, |f2-f4| ----
#pragma unroll 1
  for (int w = 0; w < 4; ++w) {
    const uint4 a = r2[w];
    const uint4 c4 = r4[w];
    const uint32 ua[4] = {a.x, a.y, a.z, a.w};
    const uint32 ub[4] = {c4.x, c4.y, c4.z, c4.w};
#pragma unroll
    for (int tq = 0; tq < 4; ++tq) {
      const int ch = w * 8 + tq * 2;
      const float a0 = bf_lo(ua[tq]), a1 = bf_hi(ua[tq]);
      const float b0 = bf_lo(ub[tq]), b1 = bf_hi(ub[tq]);
      const float s0 = a0 + b0, s1 = a1 + b1;
      const float d0 = fabsf(a0 - b0), d1 = fabsf(a1 - b1);
      const float* wps = Wt + (2 * C_IN + ch) * C_OUT;
      const float* wpd = Wt + (4 * C_IN + ch) * C_OUT;
#pragma unroll
      for (int o = 0; o < C_OUT; ++o) acc[o] += s0 * wps[o];
#pragma unroll
      for (int o = 0; o < C_OUT; ++o) acc[o] += s1 * wps[C_OUT + o];
#pragma unroll
      for (int o = 0; o < C_OUT; ++o) acc[o] += d0 * wpd[o];
#pragma unroll
      for (int o = 0; o < C_OUT; ++o) acc[o] += d1 * wpd[C_OUT + o];
    }
  }

  // ---- epilogue: bias + coalesced store (lane-consecutive e) ----
#pragma unroll
  for (int o = 0; o < C_OUT; ++o) {
    out[((long)b * C_OUT + o) * E_DIM + e] = acc[o] + bias[o];
  }
}

extern "C" void kernel_launch(void* const* d_in, const int* in_sizes, int n_in,
                              void* d_out, int out_size, void* d_ws, size_t ws_size,
                              hipStream_t stream) {
  const float* x    = (const float*)d_in[0];
  const int*   Gi   = (const int*)d_in[1];
  const float* W    = (const float*)d_in[2];
  const float* bias = (const float*)d_in[3];
  float* out = (float*)d_out;

  // workspace layout: xT packed-bf16 (B*E*16 uints = 51.2 MB), then Wt (40 KB)
  uint32* xT = (uint32*)d_ws;
  float* Wt = (float*)((char*)d_ws + (size_t)B_DIM * E_DIM * 16 * sizeof(uint32));

  dim3 gx(E_DIM / 64, B_DIM);
  xpose_kernel<<<gx, 256, 0, stream>>>(x, xT);

  prep_w<<<(C_OUT * C_IN * KNB + 255) / 256, 256, 0, stream>>>(W, Wt);

  dim3 gm((E_DIM + 255) / 256, B_DIM);
  mesh_main<<<gm, 256, 0, stream>>>(xT, Gi, Wt, bias, out);
}

// Round 2
// 459.050 us; speedup vs baseline: 1.1305x; 1.1305x over previous
//
#include <hip/hip_runtime.h>

typedef unsigned int u32;
typedef __bf16 bf16x8 __attribute__((ext_vector_type(8)));
typedef float f32x4 __attribute__((ext_vector_type(4)));
typedef u32 u32x4 __attribute__((ext_vector_type(4)));

#define B_DIM 4
#define E_DIM 200000
#define C_OUT 64
#define TPB   12500            // 16-edge tiles per batch
#define NTILE (B_DIM * TPB)    // 50000
#define KPADW 168              // A-row length in bf16: 5*32=160 data + 8 pad (bank-conflict-free)
#define ROWU  (KPADW / 2)      // 84 u32 per A row
#define WLDS  (C_OUT * ROWU)   // 5376 u32 = 21504 B

// round-half-up bf16 pack of two floats -> packed u32 (lo in low half).
// float is sign-magnitude, so +0x8000 on the bit pattern rounds the magnitude.
__device__ __forceinline__ u32 pack_bf2(float lo, float hi) {
  u32 a = __float_as_uint(lo) + 0x8000u;
  u32 b = __float_as_uint(hi) + 0x8000u;
  return __builtin_amdgcn_perm(b, a, 0x07060302u);  // [hi16(b) : hi16(a)]
}

// |bf16(a_i) - bf16(b_i)| for a packed pair, result packed bf16 (round-half-up).
__device__ __forceinline__ u32 absdiff_pack(u32 a, u32 b) {
  float alo = __uint_as_float(a << 16), ahi = __uint_as_float(a & 0xffff0000u);
  float blo = __uint_as_float(b << 16), bhi = __uint_as_float(b & 0xffff0000u);
  u32 dlo = __float_as_uint(alo - blo) + 0x8000u;
  u32 dhi = __float_as_uint(ahi - bhi) + 0x8000u;
  return __builtin_amdgcn_perm(dhi, dlo, 0x07060302u) & 0x7fff7fffu;  // packed abs
}

// ---- kernel 1: x (B,C,E) f32 -> xT (B,E,C) packed bf16; row = 64 B ----------
__global__ __launch_bounds__(256) void xpose_kernel(const float* __restrict__ x,
                                                    u32* __restrict__ xT) {
  const int e = blockIdx.x * 256 + threadIdx.x;
  const int b = blockIdx.y;
  if (e >= E_DIM) return;
  const float* xb = x + (size_t)b * 32 * E_DIM;
  u32 row[16];
#pragma unroll
  for (int u = 0; u < 16; ++u) {
    const float lo = xb[(2 * u) * E_DIM + e];       // coalesced: lane-consecutive e
    const float hi = xb[(2 * u + 1) * E_DIM + e];
    row[u] = pack_bf2(lo, hi);
  }
  uint4* dst = (uint4*)(xT + ((size_t)b * E_DIM + e) * 16);
#pragma unroll
  for (int w = 0; w < 4; ++w)
    dst[w] = make_uint4(row[4 * w], row[4 * w + 1], row[4 * w + 2], row[4 * w + 3]);
}

// ---- kernel 2: W (O,C,1,5) f32 -> Wa[o][s*32+c] bf16 packed, row pitch 84 u32
__global__ __launch_bounds__(256) void prep_w(const float* __restrict__ W,
                                              u32* __restrict__ Wa) {
  const int p = blockIdx.x * 256 + threadIdx.x;
  if (p >= C_OUT * 5 * 16) return;
  const int o = p / 80, r = p % 80, s = r / 16, cc = r % 16;
  const float w0 = W[(o * 32 + 2 * cc) * 5 + s];
  const float w1 = W[(o * 32 + 2 * cc + 1) * 5 + s];
  Wa[o * ROWU + s * 16 + cc] = pack_bf2(w0, w1);
}

// ---- kernel 3: MFMA main. wave-tile = 16 edges x 64 outs, K=224 -------------
__global__ __launch_bounds__(256, 4) void mesh_main(const u32* __restrict__ xT,
                                                    const int* __restrict__ Gi,
                                                    const u32* __restrict__ Wa,
                                                    const float* __restrict__ bias,
                                                    float* __restrict__ out) {
  __shared__ u32 Wl[WLDS];
  for (int i = threadIdx.x; i < WLDS; i += 256) Wl[i] = Wa[i];
  __syncthreads();

  const int l  = threadIdx.x & 63;
  const int wv = threadIdx.x >> 6;
  const int n  = l & 15;   // MFMA column: edge-in-tile
  const int q  = l >> 4;   // quad: k-subchunk / output row group
  const int j4 = l & 3;    // loader: uint4 index within a 64 B row
  const int eL = l >> 2;   // loader: edge-in-tile
  const int pidx = ((n << 2) | q) << 2;   // bpermute byte index: frag lane <- loader lane
  const int NW = gridDim.x * 4;

  int t = blockIdx.x * 4 + wv;

  // ---- prefetch tile t: indices + 5 gathered rows ----
  int b  = t / TPB;
  int e0 = (t - b * TPB) * 16;
  {
  }
  const int* gp = Gi + ((b * E_DIM + e0 + eL) * 5);
  int i0 = gp[0], i1 = gp[1], i2 = gp[2], i3 = gp[3], i4 = gp[4];
  const uint4* xb = (const uint4*)(xT + (size_t)b * E_DIM * 16);
  uint4 c0 = xb[i0 * 4 + j4], c1 = xb[i1 * 4 + j4], c2 = xb[i2 * 4 + j4],
        c3 = xb[i3 * 4 + j4], c4 = xb[i4 * 4 + j4];

  const f32x4* bp = (const f32x4*)bias;

  for (;;) {
    const int nt = t + NW;
    const bool has = nt < NTILE;   // wave-uniform
    int nb = 0, ne0 = 0;
    uint4 x0, x1, x2, x3, x4;
    if (has) {                      // prefetch next tile while we compute
      nb  = nt / TPB;
      ne0 = (nt - nb * TPB) * 16;
      const int* gq = Gi + ((nb * E_DIM + ne0 + eL) * 5);
      const int k0 = gq[0], k1 = gq[1], k2 = gq[2], k3 = gq[3], k4 = gq[4];
      const uint4* xn = (const uint4*)(xT + (size_t)nb * E_DIM * 16);
      x0 = xn[k0 * 4 + j4]; x1 = xn[k1 * 4 + j4]; x2 = xn[k2 * 4 + j4];
      x3 = xn[k3 * 4 + j4]; x4 = xn[k4 * 4 + j4];
    }

    // rows[slot][word]: slots 0-4 raw f0..f4, slot 5 = |f1-f3|, slot 6 = |f2-f4|
    u32 rows[7][4];
    rows[0][0] = c0.x; rows[0][1] = c0.y; rows[0][2] = c0.z; rows[0][3] = c0.w;
    rows[1][0] = c1.x; rows[1][1] = c1.y; rows[1][2] = c1.z; rows[1][3] = c1.w;
    rows[2][0] = c2.x; rows[2][1] = c2.y; rows[2][2] = c2.z; rows[2][3] = c2.w;
    rows[3][0] = c3.x; rows[3][1] = c3.y; rows[3][2] = c3.z; rows[3][3] = c3.w;
    rows[4][0] = c4.x; rows[4][1] = c4.y; rows[4][2] = c4.z; rows[4][3] = c4.w;
#pragma unroll
    for (int wd = 0; wd < 4; ++wd) {
      rows[5][wd] = absdiff_pack(rows[1][wd], rows[3][wd]);
      rows[6][wd] = absdiff_pack(rows[2][wd], rows[4][wd]);
    }

    // accumulators init = bias (D row = quad*4 + reg)
    f32x4 acc0 = bp[0 * 4 + q];
    f32x4 acc1 = bp[1 * 4 + q];
    f32x4 acc2 = bp[2 * 4 + q];
    f32x4 acc3 = bp[3 * 4 + q];

    // weight slot per k-chunk: out = W0 f0 + W1(f1+f3) + W2(f2+f4) + W3|f1-f3| + W4|f2-f4|
    const int aslot[7] = {0, 1, 2, 1, 2, 3, 4};
#pragma unroll
    for (int kc = 0; kc < 7; ++kc) {
      union { u32 u[4]; bf16x8 v; } bu;
#pragma unroll
      for (int c = 0; c < 4; ++c)
        bu.u[c] = (u32)__builtin_amdgcn_ds_bpermute(pidx, (int)rows[kc][c]);
      const int wbase = n * ROWU + aslot[kc] * 16 + q * 4;  // u32 index, 16B-aligned
      union { u32x4 u; bf16x8 v; } a0, a1, a2, a3;
      a0.u = *(const u32x4*)(Wl + wbase);
      a1.u = *(const u32x4*)(Wl + wbase + 16 * ROWU);
      a2.u = *(const u32x4*)(Wl + wbase + 32 * ROWU);
      a3.u = *(const u32x4*)(Wl + wbase + 48 * ROWU);
      acc0 = __builtin_amdgcn_mfma_f32_16x16x32_bf16(a0.v, bu.v, acc0, 0, 0, 0);
      acc1 = __builtin_amdgcn_mfma_f32_16x16x32_bf16(a1.v, bu.v, acc1, 0, 0, 0);
      acc2 = __builtin_amdgcn_mfma_f32_16x16x32_bf16(a2.v, bu.v, acc2, 0, 0, 0);
      acc3 = __builtin_amdgcn_mfma_f32_16x16x32_bf16(a3.v, bu.v, acc3, 0, 0, 0);
    }

    // store: D[row = q*4+r][col = n]; out[b][o][e]
    float* ob = out + ((b * C_OUT + q * 4) * E_DIM + e0 + n);
#pragma unroll
    for (int r = 0; r < 4; ++r) {
      ob[(0 * 16 + r) * E_DIM] = acc0[r];
      ob[(1 * 16 + r) * E_DIM] = acc1[r];
      ob[(2 * 16 + r) * E_DIM] = acc2[r];
      ob[(3 * 16 + r) * E_DIM] = acc3[r];
    }

    if (!has) break;
    t = nt; b = nb; e0 = ne0;
    c0 = x0; c1 = x1; c2 = x2; c3 = x3; c4 = x4;
  }
}

extern "C" void kernel_launch(void* const* d_in, const int* in_sizes, int n_in,
                              void* d_out, int out_size, void* d_ws, size_t ws_size,
                              hipStream_t stream) {
  const float* x    = (const float*)d_in[0];
  const int*   Gi   = (const int*)d_in[1];
  const float* W    = (const float*)d_in[2];
  const float* bias = (const float*)d_in[3];
  float* out = (float*)d_out;

  // workspace: xT packed-bf16 (B*E*16 u32 = 51.2 MB), then Wa (21.5 KB)
  u32* xT = (u32*)d_ws;
  u32* Wa = xT + (size_t)B_DIM * E_DIM * 16;

  dim3 gx((E_DIM + 255) / 256, B_DIM);
  xpose_kernel<<<gx, 256, 0, stream>>>(x, xT);

  prep_w<<<(C_OUT * 5 * 16 + 255) / 256, 256, 0, stream>>>(W, Wa);

  mesh_main<<<1024, 256, 0, stream>>>(xT, Gi, Wa, bias, out);
}

// Round 3
// 392.887 us; speedup vs baseline: 1.3209x; 1.1684x over previous
//
#include <hip/hip_runtime.h>

typedef unsigned int u32;
typedef __bf16 bf16x8 __attribute__((ext_vector_type(8)));
typedef float f32x4 __attribute__((ext_vector_type(4)));

#define B_DIM 4
#define E_DIM 200000
#define C_OUT 64
#define TPB   12500            // 16-edge tiles per batch
#define NT    (B_DIM * TPB)    // 50000 tiles
#define NBLK  1280             // 5 blocks/CU (LDS-limited), 5120 waves
#define WLDS_U4 1792           // weight LDS: 7 chunks * 4 quads * 64 outs uint4
// flat u32 layout for swizzled weights: ((s*4+q)*64 + o)*4 + r

// round-half-up bf16 pack of two floats -> packed u32 (lo in low half).
// float is sign-magnitude, so +0x8000 on the bit pattern rounds the magnitude.
__device__ __forceinline__ u32 pack_bf2(float lo, float hi) {
  u32 a = __float_as_uint(lo) + 0x8000u;
  u32 b = __float_as_uint(hi) + 0x8000u;
  return __builtin_amdgcn_perm(b, a, 0x07060302u);  // [hi16(b) : hi16(a)]
}

// |bf16(a_i) - bf16(b_i)| for a packed pair, result packed bf16.
__device__ __forceinline__ u32 absdiff_pack(u32 a, u32 b) {
  float alo = __uint_as_float(a << 16), ahi = __uint_as_float(a & 0xffff0000u);
  float blo = __uint_as_float(b << 16), bhi = __uint_as_float(b & 0xffff0000u);
  u32 dlo = __float_as_uint(alo - blo) + 0x8000u;
  u32 dhi = __float_as_uint(ahi - bhi) + 0x8000u;
  return __builtin_amdgcn_perm(dhi, dlo, 0x07060302u) & 0x7fff7fffu;
}

__device__ __forceinline__ uint4 absdiff_vec(uint4 a, uint4 b) {
  return make_uint4(absdiff_pack(a.x, b.x), absdiff_pack(a.y, b.y),
                    absdiff_pack(a.z, b.z), absdiff_pack(a.w, b.w));
}

// ---- kernel 1: x (B,C,E) f32 -> xT (B,E,C) packed bf16; row = 64 B ----------
// LDS-staged: both global reads and global writes fully coalesced.
__global__ __launch_bounds__(256) void xpose_kernel(const float* __restrict__ x,
                                                    u32* __restrict__ xT) {
  __shared__ u32 T[256 * 17];  // pitch 17: conflict-free scattered writes
  const int b = blockIdx.y;
  const int e0 = blockIdx.x * 256;
  const int t = threadIdx.x;
  const int nrows = min(256, E_DIM - e0);
  const float* xb = x + (size_t)b * 32 * E_DIM + e0;
  if (t < nrows) {
#pragma unroll
    for (int u = 0; u < 16; ++u) {
      const float lo = xb[(size_t)(2 * u) * E_DIM + t];      // coalesced
      const float hi = xb[(size_t)(2 * u + 1) * E_DIM + t];
      T[t * 17 + u] = pack_bf2(lo, hi);
    }
  }
  __syncthreads();
  const int total = nrows * 16;
  u32* dst = xT + ((size_t)b * E_DIM + e0) * 16;
#pragma unroll
  for (int k = 0; k < 16; ++k) {
    const int g = t + k * 256;
    if (g < total) dst[g] = T[(g >> 4) * 17 + (g & 15)];     // coalesced store
  }
}

// ---- kernel 2: W (O=64, C=32, 1, K=5) f32 -> swizzled bf16 A-operand --------
// Wa2[((s*4+q)*64 + o)*4 + r] = pack(W[o][q*8+2r][kmap[s]], W[o][q*8+2r+1][kmap[s]])
// K-chunks s=0..6 multiply {f0, f1, f2, f3, f4, |f1-f3|, |f2-f4|}:
// out = W0 f0 + W1 f1 + W2 f2 + W1 f3 + W2 f4 + W3|f1-f3| + W4|f2-f4|
__global__ __launch_bounds__(256) void prep_w(const float* __restrict__ W,
                                              u32* __restrict__ Wa2) {
  const int p = blockIdx.x * 256 + threadIdx.x;
  if (p >= 7168) return;
  const int r = p & 3;
  const int o = (p >> 2) & 63;
  const int q = (p >> 8) & 3;
  const int s = p >> 10;
  const int kmap[7] = {0, 1, 2, 1, 2, 3, 4};
  const int c0 = q * 8 + 2 * r;
  const float w0 = W[(o * 32 + c0) * 5 + kmap[s]];
  const float w1 = W[(o * 32 + c0 + 1) * 5 + kmap[s]];
  Wa2[p] = pack_bf2(w0, w1);
}

// ---- kernel 3: MFMA main, 16 edges x 64 outs per wave-tile ------------------
// Identity gather layout: lane (n = l&15 edge, q = l>>4 quad) loads uint4 j4=q
// of the gathered row -> that register IS the MFMA B-fragment (no bpermute).
// 3-stage pipeline: Gi two tiles ahead, gathers one tile ahead.
__global__ __launch_bounds__(256) void mesh_main(const u32* __restrict__ xT,
                                                 const int* __restrict__ Gi,
                                                 const u32* __restrict__ Wa2,
                                                 const float* __restrict__ bias,
                                                 float* __restrict__ out) {
  __shared__ uint4 Wl[WLDS_U4];  // 28 KB
  {
    const uint4* src = (const uint4*)Wa2;
#pragma unroll
    for (int k = 0; k < 7; ++k) Wl[threadIdx.x + k * 256] = src[threadIdx.x + k * 256];
  }
  __syncthreads();

  const int l = threadIdx.x & 63;
  const int wv = threadIdx.x >> 6;
  const int n = l & 15;   // edge-in-tile == B-frag column
  const int q = l >> 4;   // quad == loader j4 == B-frag k-group
  const int NW = NBLK * 4;

  // bias preload: acc row o = og*16 + q*4 + r
  f32x4 bv[4];
#pragma unroll
  for (int og = 0; og < 4; ++og) bv[og] = *(const f32x4*)(bias + og * 16 + q * 4);

  const uint4* xb4 = (const uint4*)xT;

  int t = blockIdx.x * 4 + wv;          // < 5120 < NT always

  // ---- prologue: Gi(t) -> gather(t) -> Gi(t+NW) ----
  int gcur[5], gnext[5];
  {
    const int b = t / TPB;
    const int e = (t - b * TPB) * 16 + n;
    const int* gp = Gi + (b * E_DIM + e) * 5;
#pragma unroll
    for (int s = 0; s < 5; ++s) gcur[s] = b * E_DIM + gp[s];
  }
  uint4 cur[5];
#pragma unroll
  for (int s = 0; s < 5; ++s) cur[s] = xb4[(size_t)gcur[s] * 4 + q];

  int t1 = t + NW;
  if (t1 < NT) {
    const int b = t1 / TPB;
    const int e = (t1 - b * TPB) * 16 + n;
    const int* gp = Gi + (b * E_DIM + e) * 5;
#pragma unroll
    for (int s = 0; s < 5; ++s) gnext[s] = b * E_DIM + gp[s];
  }

  for (;;) {
    const bool has = t1 < NT;  // wave-uniform
    // stage B: gather tile t1 (Gi already resident for >=1 iteration)
    uint4 nxt[5];
    if (has) {
#pragma unroll
      for (int s = 0; s < 5; ++s) nxt[s] = xb4[(size_t)gnext[s] * 4 + q];
    }
    // stage A: Gi for tile t1+NW
    const int t2 = t1 + NW;
    if (t2 < NT) {
      const int b = t2 / TPB;
      const int e = (t2 - b * TPB) * 16 + n;
      const int* gp = Gi + (b * E_DIM + e) * 5;
#pragma unroll
      for (int s = 0; s < 5; ++s) gnext[s] = b * E_DIM + gp[s];
    }

    // stage C: compute tile t
    union { uint4 u; bf16x8 v; } frag[7];
#pragma unroll
    for (int s = 0; s < 5; ++s) frag[s].u = cur[s];
    frag[5].u = absdiff_vec(cur[1], cur[3]);
    frag[6].u = absdiff_vec(cur[2], cur[4]);

    f32x4 acc0 = bv[0], acc1 = bv[1], acc2 = bv[2], acc3 = bv[3];
#pragma unroll
    for (int c = 0; c < 7; ++c) {
      const uint4* wp = Wl + (c * 4 + q) * 64 + n;
      union { uint4 u; bf16x8 v; } a0, a1, a2, a3;
      a0.u = wp[0];
      a1.u = wp[16];
      a2.u = wp[32];
      a3.u = wp[48];
      acc0 = __builtin_amdgcn_mfma_f32_16x16x32_bf16(a0.v, frag[c].v, acc0, 0, 0, 0);
      acc1 = __builtin_amdgcn_mfma_f32_16x16x32_bf16(a1.v, frag[c].v, acc1, 0, 0, 0);
      acc2 = __builtin_amdgcn_mfma_f32_16x16x32_bf16(a2.v, frag[c].v, acc2, 0, 0, 0);
      acc3 = __builtin_amdgcn_mfma_f32_16x16x32_bf16(a3.v, frag[c].v, acc3, 0, 0, 0);
    }

    // store: o = og*16 + q*4 + r, e = e0 + n
    {
      const int b = t / TPB;
      const int e0 = (t - b * TPB) * 16;
      float* ob = out + ((size_t)(b * C_OUT + q * 4) * E_DIM + e0 + n);
#pragma unroll
      for (int r = 0; r < 4; ++r) {
        ob[(size_t)(0 * 16 + r) * E_DIM] = acc0[r];
        ob[(size_t)(1 * 16 + r) * E_DIM] = acc1[r];
        ob[(size_t)(2 * 16 + r) * E_DIM] = acc2[r];
        ob[(size_t)(3 * 16 + r) * E_DIM] = acc3[r];
      }
    }

    if (!has) break;
    t = t1;
    t1 = t2;
#pragma unroll
    for (int s = 0; s < 5; ++s) cur[s] = nxt[s];
  }
}

extern "C" void kernel_launch(void* const* d_in, const int* in_sizes, int n_in,
                              void* d_out, int out_size, void* d_ws, size_t ws_size,
                              hipStream_t stream) {
  const float* x    = (const float*)d_in[0];
  const int*   Gi   = (const int*)d_in[1];
  const float* W    = (const float*)d_in[2];
  const float* bias = (const float*)d_in[3];
  float* out = (float*)d_out;

  // workspace: xT packed-bf16 (B*E*16 u32 = 51.2 MB), then Wa2 (28 KB)
  u32* xT  = (u32*)d_ws;
  u32* Wa2 = xT + (size_t)B_DIM * E_DIM * 16;

  dim3 gx((E_DIM + 255) / 256, B_DIM);
  xpose_kernel<<<gx, 256, 0, stream>>>(x, xT);

  prep_w<<<28, 256, 0, stream>>>(W, Wa2);

  mesh_main<<<NBLK, 256, 0, stream>>>(xT, Gi, Wa2, bias, out);
}